// Round 2
// baseline (960.561 us; speedup 1.0000x reference)
//
#include <hip/hip_runtime.h>
#include <cstdint>

#define CC 512
#define AA 256
#define NBLK 256   // fused grid: 1 block per CU
#define TPB 8      // r-tiles (128 rows) per block: 256*8*128 = 262144 rows

typedef __bf16 bf16x8 __attribute__((ext_vector_type(8)));
typedef float f32x16 __attribute__((ext_vector_type(16)));

__device__ __forceinline__ unsigned short f2bf(float f) {
  union { float f; uint32_t u; } v; v.f = f;
  return (unsigned short)((v.u + 0x7FFFu + ((v.u >> 16) & 1u)) >> 16);
}

// ---------------- prep: attn2 = Ua.q + Ua_b + Wa_b ; Wa -> bf16 --------------
__global__ void prep_kernel(const float* __restrict__ q,
                            const float* __restrict__ Wa_w,
                            const float* __restrict__ Wa_b,
                            const float* __restrict__ Ua_w,
                            const float* __restrict__ Ua_b,
                            unsigned short* __restrict__ wa_bf,
                            float* __restrict__ attn2) {
  const int blk = blockIdx.x, t = threadIdx.x;
  if (blk < 64) {
    const int b = blk, a = t;
    float acc = Ua_b[a] + Wa_b[a];
    const float4* qr = (const float4*)(q + (size_t)b * CC);
    const float4* ur = (const float4*)(Ua_w + (size_t)a * CC);
#pragma unroll 4
    for (int i = 0; i < CC / 4; ++i) {
      float4 uu = ur[i], qq = qr[i];
      acc += uu.x * qq.x + uu.y * qq.y + uu.z * qq.z + uu.w * qq.w;
    }
    attn2[b * AA + a] = acc;
  } else {
    const int base = (blk - 64) * 2048 + t * 8;
#pragma unroll
    for (int i = 0; i < 8; ++i) wa_bf[base + i] = f2bf(Wa_w[base + i]);
  }
}

// ---------------- fused: scores GEMM -> u=exp(s) -> partial context ----------
// Block tile per r-tile: M=128 rows (r=p*64+b), N=256 (all A), K=512, BK=64.
// 8 waves in 2(M)x4(N) grid; wave tile 64x64 via 2x2 mfma_32x32x16 -> acc=64 regs.
// No softmax max needed: |s| <= sum|va|+|va_b| ~ 4.2, exp(s) safe in fp32.
__global__ __launch_bounds__(512, 2) void fused_kernel(
    const float* __restrict__ keys,
    const unsigned short* __restrict__ wa_bf,
    const float* __restrict__ attn2,
    const float* __restrict__ va_w,
    const float* __restrict__ va_b,
    float* __restrict__ u_g,      // exp(scores), [262144]
    float* __restrict__ cpart,    // [NBLK][64][512]
    float* __restrict__ zpart) {  // [NBLK][64]
  __shared__ __align__(16) unsigned short As[128 * 72];
  __shared__ __align__(16) unsigned short Bs[256 * 72];
  __shared__ float sc[4][128];
  __shared__ __align__(16) float u_s[128];
  __shared__ float zp_s[64];

  const int t = threadIdx.x;
  const int w = t >> 6, lane = t & 63, m32 = lane & 31, kg = lane >> 5;
  const int R0w = (w & 1) * 64, C0w = (w >> 1) * 64;

  float Cown[64];  // per-thread: column c=t of partial context, all 64 b
#pragma unroll
  for (int b = 0; b < 64; ++b) Cown[b] = 0.f;
  if (t < 64) zp_s[t] = 0.f;
  __syncthreads();

  const int c4 = t & 15, rg = t >> 4;  // A staging: 16 float4-cols x 32 rows/pass
  const int kq = t & 7, ng = t >> 3;   // B staging: 8 x16B-cols x 64 rows/pass

  for (int tile = 0; tile < TPB; ++tile) {
    const long r0 = ((long)blockIdx.x * TPB + tile) * 128;

    f32x16 acc[2][2];
#pragma unroll
    for (int i = 0; i < 2; ++i)
#pragma unroll
      for (int j = 0; j < 2; ++j)
#pragma unroll
        for (int e = 0; e < 16; ++e) acc[i][j][e] = 0.f;

    for (int ko = 0; ko < 8; ++ko) {
      const int kb = ko * 64;
#pragma unroll
      for (int ps = 0; ps < 4; ++ps) {   // keys fp32 -> bf16 -> LDS
        const int row = rg + ps * 32;
        float4 v = *(const float4*)(keys + (size_t)(r0 + row) * CC + kb + c4 * 4);
        ushort4 h;
        h.x = f2bf(v.x); h.y = f2bf(v.y); h.z = f2bf(v.z); h.w = f2bf(v.w);
        *(ushort4*)(As + row * 72 + c4 * 4) = h;
      }
#pragma unroll
      for (int ps = 0; ps < 4; ++ps) {   // Wa bf16 -> LDS
        const int n = ng + ps * 64;
        int4 v = *(const int4*)(wa_bf + (size_t)n * CC + kb + kq * 8);
        *(int4*)(Bs + n * 72 + kq * 8) = v;
      }
      __syncthreads();
#pragma unroll
      for (int kk = 0; kk < 4; ++kk) {
        const int k0 = kk * 16 + kg * 8;
        bf16x8 a0 = *(const bf16x8*)(As + (R0w + m32) * 72 + k0);
        bf16x8 a1 = *(const bf16x8*)(As + (R0w + 32 + m32) * 72 + k0);
        bf16x8 b0 = *(const bf16x8*)(Bs + (C0w + m32) * 72 + k0);
        bf16x8 b1 = *(const bf16x8*)(Bs + (C0w + 32 + m32) * 72 + k0);
        acc[0][0] = __builtin_amdgcn_mfma_f32_32x32x16_bf16(a0, b0, acc[0][0], 0, 0, 0);
        acc[0][1] = __builtin_amdgcn_mfma_f32_32x32x16_bf16(a0, b1, acc[0][1], 0, 0, 0);
        acc[1][0] = __builtin_amdgcn_mfma_f32_32x32x16_bf16(a1, b0, acc[1][0], 0, 0, 0);
        acc[1][1] = __builtin_amdgcn_mfma_f32_32x32x16_bf16(a1, b1, acc[1][1], 0, 0, 0);
      }
      __syncthreads();
    }

    // ---- epilogue: s = va . tanh(acc + attn2) ----
    // C/D layout (m74/m101): col = nt*32+(lane&31); row = (r&3)+8*(r>>2)+4*kg.
#pragma unroll
    for (int mt = 0; mt < 2; ++mt) {
      float ps_[16];
#pragma unroll
      for (int r = 0; r < 16; ++r) ps_[r] = 0.f;
      const int rowb = R0w + mt * 32 + 4 * kg;
#pragma unroll
      for (int nt = 0; nt < 2; ++nt) {
        const int col = C0w + nt * 32 + m32;
        const float vv = va_w[col];
#pragma unroll
        for (int r = 0; r < 16; ++r) {
          const int row = rowb + (r & 3) + 8 * (r >> 2);
          float x = acc[mt][nt][r] + attn2[(row & 63) * AA + col];
          float ax = fabsf(x);
          float e2 = __expf(-2.f * ax);
          float th = (1.f - e2) / (1.f + e2);
          ps_[r] += copysignf(th, x) * vv;
        }
      }
#pragma unroll
      for (int off = 1; off <= 16; off <<= 1)
#pragma unroll
        for (int r = 0; r < 16; ++r) ps_[r] += __shfl_xor(ps_[r], off);
      if (m32 == 0) {
#pragma unroll
        for (int r = 0; r < 16; ++r)
          sc[w >> 1][rowb + (r & 3) + 8 * (r >> 2)] = ps_[r];
      }
    }
    __syncthreads();
    if (t < 64) {
      float s0 = sc[0][t] + sc[1][t] + sc[2][t] + sc[3][t] + va_b[0];
      float s1 = sc[0][t + 64] + sc[1][t + 64] + sc[2][t + 64] + sc[3][t + 64] + va_b[0];
      float e0 = __expf(s0), e1 = __expf(s1);
      u_s[t] = e0; u_s[t + 64] = e1;
      u_g[r0 + t] = e0; u_g[r0 + 64 + t] = e1;
      zp_s[t] += e0 + e1;
    }
    __syncthreads();

    // ---- partial context: Cown[b] += u[p0,b]*k[p0,b,t] + u[p0+1,b]*k[..] ----
    // keys re-read is L2-warm (this block just streamed the tile).
    const float* krow = keys + (size_t)r0 * CC + t;
#pragma unroll
    for (int b4 = 0; b4 < 16; ++b4) {
      float4 ua = *(const float4*)&u_s[b4 * 4];
      float4 ub = *(const float4*)&u_s[b4 * 4 + 64];
      const float* uap = (const float*)&ua;
      const float* ubp = (const float*)&ub;
#pragma unroll
      for (int j = 0; j < 4; ++j) {
        const int b = b4 * 4 + j;
        float k0v = krow[(size_t)b * CC];
        float k1v = krow[(size_t)(b + 64) * CC];
        Cown[b] += uap[j] * k0v + ubp[j] * k1v;
      }
    }
    // no barrier needed: next-tile staging touches only As/Bs; u_s/sc are
    // rewritten only after the next ko-loop's 16 barriers.
  }

  const size_t base = (size_t)blockIdx.x * 32768;
#pragma unroll
  for (int b = 0; b < 64; ++b) cpart[base + b * 512 + t] = Cown[b];
  if (t < 64) zpart[blockIdx.x * 64 + t] = zp_s[t];
}

// ---------------- reduce: Csum[b][c] = sum_blk Cpart ; Z[b] = sum_blk Zpart --
__global__ void reduce_kernel(const float* __restrict__ cpart,
                              const float* __restrict__ zpart,
                              float* __restrict__ csum,
                              float* __restrict__ zsum) {
  const int t = threadIdx.x;
  if (blockIdx.x < 128) {
    const int j = blockIdx.x * 256 + t;
    float s = 0.f;
#pragma unroll 8
    for (int k = 0; k < NBLK; ++k) s += cpart[(size_t)k * 32768 + j];
    csum[j] = s;
  } else if (t < 64) {
    float s = 0.f;
#pragma unroll 8
    for (int k = 0; k < NBLK; ++k) s += zpart[k * 64 + t];
    zsum[t] = s;
  }
}

// ---------------- finalize: context = Csum/Z ; weights = u/Z -----------------
__global__ void finalize_kernel(const float* __restrict__ csum,
                                const float* __restrict__ zsum,
                                const float* __restrict__ u_g,
                                float* __restrict__ out) {
  const int gid = blockIdx.x * 256 + threadIdx.x;
  const int j = gid * 4;
  if (j < 32768) {
    const int b = j >> 9;
    const float invZ = 1.f / zsum[b];
    float4 c = *(const float4*)(csum + j);
    c.x *= invZ; c.y *= invZ; c.z *= invZ; c.w *= invZ;
    *(float4*)(out + j) = c;
  } else {
    const int r = j - 32768;  // r = p*64+b, spans b0..b0+3, b0 = r&63 (mult of 4)
    float4 uu = *(const float4*)(u_g + r);
    float4 zz = *(const float4*)(zsum + (r & 63));
    float4 ww;
    ww.x = uu.x / zz.x; ww.y = uu.y / zz.y;
    ww.z = uu.z / zz.z; ww.w = uu.w / zz.w;
    *(float4*)(out + 32768 + r) = ww;
  }
}

extern "C" void kernel_launch(void* const* d_in, const int* in_sizes, int n_in,
                              void* d_out, int out_size, void* d_ws, size_t ws_size,
                              hipStream_t stream) {
  (void)in_sizes; (void)n_in; (void)out_size; (void)ws_size;
  const float* keys = (const float*)d_in[0];
  const float* q    = (const float*)d_in[1];
  const float* Wa_w = (const float*)d_in[2];
  const float* Wa_b = (const float*)d_in[3];
  const float* Ua_w = (const float*)d_in[4];
  const float* Ua_b = (const float*)d_in[5];
  const float* va_w = (const float*)d_in[6];
  const float* va_b = (const float*)d_in[7];
  float* out = (float*)d_out;

  // ws: wa_bf 256KB | attn2 64KB | u 1MB | cpart 32MB | zpart 64KB | csum 128KB | zsum
  unsigned short* wa_bf = (unsigned short*)d_ws;
  float* attn2 = (float*)((char*)d_ws + 262144);
  float* u_g   = (float*)((char*)d_ws + 327680);
  float* cpart = (float*)((char*)d_ws + 1376256);
  float* zpart = (float*)((char*)d_ws + 34930688);
  float* csum  = (float*)((char*)d_ws + 34996224);
  float* zsum  = (float*)((char*)d_ws + 35127296);

  prep_kernel<<<128, 256, 0, stream>>>(q, Wa_w, Wa_b, Ua_w, Ua_b, wa_bf, attn2);
  fused_kernel<<<NBLK, 512, 0, stream>>>(keys, wa_bf, attn2, va_w, va_b,
                                         u_g, cpart, zpart);
  reduce_kernel<<<129, 256, 0, stream>>>(cpart, zpart, csum, zsum);
  finalize_kernel<<<288, 256, 0, stream>>>(csum, zsum, u_g, out);
}